// Round 23
// baseline (50.942 us; speedup 1.0000x reference)
//
#include <hip/hip_runtime.h>
#include <hip/hip_bf16.h>

#define EPS 1e-12f
// Features stored pre-scaled by sqrt(C_EXP), C_EXP=(1/0.07)*log2(e):
// MFMA output acc = C_EXP*(f_i.f_j) is exp2-ready; possum = (pp-sq_s)*ln2.
#define SQRT_C_EXP 4.53981597f
#define M_LN2F 0.69314718056f
#define NUM_CLASSES 16

#define BM 256          // rows per denom block
#define BN 128          // cols per chunk
#define KD 128          // feature dim
#define NCHUNK 8        // col chunks per colgroup (1024 cols)
#define PSTRIDE 16      // 8 expsum + 8 possum slots per row

typedef __attribute__((ext_vector_type(4))) float f32x4;
typedef __attribute__((ext_vector_type(8))) short bf16x8;

__device__ __forceinline__ float bf2f(ushort u) {
    unsigned int x = ((unsigned int)u) << 16;
    return __uint_as_float(x);
}

// Direct global->LDS 16B/lane DMA; XOR swizzle pre-applied to the GLOBAL
// source (involution), LDS dest stays linear -> layout matches lds_frag.
__device__ __forceinline__ void gload16(const void* g, void* l) {
    __builtin_amdgcn_global_load_lds(
        (const __attribute__((address_space(1))) void*)g,
        (__attribute__((address_space(3))) void*)l, 16, 0, 0);
}

// Swizzled LDS fragment address: element (r, slot) of a [rows][128] bf16 tile,
// slot = 16B chunk within the 256B row. Swizzle: slot ^= (r&7).
__device__ __forceinline__ const bf16x8* lds_frag(const ushort* base, int r, int slot) {
    int sw = slot ^ (r & 7);
    return reinterpret_cast<const bf16x8*>(
        reinterpret_cast<const char*>(base) + r * 256 + sw * 16);
}

// ---------------- Kernel A: L2-normalize rows -> bf16 (pre-scaled) ----------
// One wave per row. Block 0 additionally computes the 16-bin label histogram
// (register counts, no atomics) -> cnt16[].
__global__ void normalize_kernel(const float* __restrict__ feat,
                                 const int* __restrict__ labels,
                                 ushort* __restrict__ fb,
                                 float* __restrict__ sq,
                                 float* __restrict__ cnt16,
                                 int N) {
    const int tid  = threadIdx.x;
    const int lane = tid & 63;
    const int w    = tid >> 6;
    int r = (blockIdx.x * blockDim.x + tid) >> 6;
    if (r < N) {
        const float2 v = *reinterpret_cast<const float2*>(feat + (size_t)r * KD + lane * 2);
        float s = v.x * v.x + v.y * v.y;
        #pragma unroll
        for (int off = 1; off < 64; off <<= 1) s += __shfl_xor(s, off);
        const float scale = SQRT_C_EXP / fmaxf(sqrtf(s), EPS);

        __hip_bfloat16 h0 = __float2bfloat16(v.x * scale);
        __hip_bfloat16 h1 = __float2bfloat16(v.y * scale);
        ushort u0 = *reinterpret_cast<ushort*>(&h0);
        ushort u1 = *reinterpret_cast<ushort*>(&h1);
        unsigned int pack = (unsigned int)u0 | ((unsigned int)u1 << 16);
        *reinterpret_cast<unsigned int*>(fb + (size_t)r * KD + lane * 2) = pack;

        float q0 = bf2f(u0), q1 = bf2f(u1);
        float q = q0 * q0 + q1 * q1;
        #pragma unroll
        for (int off = 1; off < 64; off <<= 1) q += __shfl_xor(q, off);
        if (lane == 0) sq[r] = q;                 // sq_s = C_EXP*||f||^2
    }

    if (blockIdx.x == 0) {
        int cl[NUM_CLASSES];
        #pragma unroll
        for (int c = 0; c < NUM_CLASSES; c++) cl[c] = 0;
        for (int i = tid; i < N; i += 256) {
            int lb = labels[i];
            #pragma unroll
            for (int c = 0; c < NUM_CLASSES; c++) cl[c] += (lb == c) ? 1 : 0;
        }
        #pragma unroll
        for (int c = 0; c < NUM_CLASSES; c++) {
            int v = cl[c];
            #pragma unroll
            for (int off = 1; off < 64; off <<= 1) v += __shfl_xor(v, off);
            cl[c] = v;
        }
        __shared__ int hw[4][NUM_CLASSES];
        if (lane == 0) {
            #pragma unroll
            for (int c = 0; c < NUM_CLASSES; c++) hw[w][c] = cl[c];
        }
        __syncthreads();
        if (tid < NUM_CLASSES)
            cnt16[tid] = (float)(hw[0][tid] + hw[1][tid] + hw[2][tid] + hw[3][tid]);
    }
}

// ---------------- Kernel B: fused denom+possum partials (r22 best) ----------
// 256 blocks (8 colgroups x 32 rowblocks), 512 thr = 8 waves in 8x1:
// each wave owns 32 ROWS x all 128 cols of each chunk. Live set by census:
// a[4][2]=32 + pd/pp[2][4]=16 + rlab=8 + acc[2][2]=16 + addr ~20 = ~95 regs
// -> fits the native 128 budget, A-array stays RESIDENT (no LDS remat).
__global__ __launch_bounds__(512) void supcon_denom(
    const ushort* __restrict__ fb,
    const int* __restrict__ labels,
    float* __restrict__ part,
    int N) {

    __shared__ __align__(16) ushort As[BM * KD];        // 64 KB
    __shared__ __align__(16) ushort Bs[2][BN * KD];     // 2 x 32 KB

    const int tid  = threadIdx.x;
    const int lane = tid & 63;
    const int w    = tid >> 6;        // 0..7 (32-row band)
    const int r16  = lane & 15;
    const int g4   = lane >> 4;       // 0..3

    const int rowbase = blockIdx.y * BM;
    const int col0    = blockIdx.x * (BN * NCHUNK);

    // ---- stage A tile (64KB = 8 DMA) + B chunk 0 (32KB = 4 DMA) ----
    {
        const ushort* gA = fb + (size_t)rowbase * KD;
        #pragma unroll
        for (int i = 0; i < 8; i++) {
            int d = i * 512 + tid;                  // linear 16B-chunk index
            int s = d ^ ((d >> 4) & 7);             // pre-swizzled source
            gload16(gA + (size_t)s * 8, &As[d * 8]);
        }
        const ushort* gB = fb + (size_t)col0 * KD;
        #pragma unroll
        for (int i = 0; i < 4; i++) {
            int d = i * 512 + tid;
            int s = d ^ ((d >> 4) & 7);
            gload16(gB + (size_t)s * 8, &Bs[0][d * 8]);
        }
    }

    // row labels for this lane's 8 output rows (L2-hot, overlaps DMA)
    int rlab[2][4];
    #pragma unroll
    for (int m = 0; m < 2; m++)
        #pragma unroll
        for (int i = 0; i < 4; i++)
            rlab[m][i] = labels[rowbase + w * 32 + m * 16 + g4 * 4 + i];

    __syncthreads();

    // ---- A fragments (32 rows x K=128 = 8 frags = 32 VGPR), resident ----
    bf16x8 a[4][2];                   // [ks][m], static indexing only
    #pragma unroll
    for (int ks = 0; ks < 4; ks++) {
        const int slot = ks * 4 + g4;
        #pragma unroll
        for (int m = 0; m < 2; m++)
            a[ks][m] = *lds_frag(As, w * 32 + m * 16 + r16, slot);
    }

    float pd[2][4], pp[2][4];
    #pragma unroll
    for (int m = 0; m < 2; m++)
        #pragma unroll
        for (int i = 0; i < 4; i++) { pd[m][i] = 0.f; pp[m][i] = 0.f; }

    int cur = 0;
    for (int c = 0; c < NCHUNK; c++) {
        // issue next-chunk DMA into the other buffer (drained by the barrier)
        if (c + 1 < NCHUNK) {
            const ushort* gB = fb + (size_t)(col0 + (c + 1) * BN) * KD;
            ushort* dstb = Bs[cur ^ 1];
            #pragma unroll
            for (int i = 0; i < 4; i++) {
                int d = i * 512 + tid;
                int s = d ^ ((d >> 4) & 7);
                gload16(gB + (size_t)s * 8, &dstb[d * 8]);
            }
        }

        const ushort* bbase = Bs[cur];
        const int colbase = col0 + c * BN;

        #pragma unroll 1                       // 2 cols of 16 per iteration
        for (int n2 = 0; n2 < 4; n2++) {
            int clab[2];
            #pragma unroll
            for (int j = 0; j < 2; j++)
                clab[j] = labels[colbase + (n2 * 2 + j) * 16 + r16];

            f32x4 acc[2][2];
            #pragma unroll
            for (int m = 0; m < 2; m++)
                #pragma unroll
                for (int j = 0; j < 2; j++) acc[m][j] = f32x4{0.f, 0.f, 0.f, 0.f};

            #pragma unroll
            for (int ks = 0; ks < 4; ks++) {
                const int slot = ks * 4 + g4;
                bf16x8 bv[2];
                #pragma unroll
                for (int j = 0; j < 2; j++)
                    bv[j] = *lds_frag(bbase, (n2 * 2 + j) * 16 + r16, slot);
                #pragma unroll
                for (int m = 0; m < 2; m++)
                    #pragma unroll
                    for (int j = 0; j < 2; j++)
                        acc[m][j] = __builtin_amdgcn_mfma_f32_16x16x32_bf16(a[ks][m], bv[j], acc[m][j], 0, 0, 0);
            }

            #pragma unroll
            for (int m = 0; m < 2; m++)
                #pragma unroll
                for (int j = 0; j < 2; j++)
                    #pragma unroll
                    for (int i = 0; i < 4; i++) {
                        const float sim = acc[m][j][i];
                        pd[m][i] += __builtin_amdgcn_exp2f(sim);
                        pp[m][i] += (rlab[m][i] == clab[j]) ? sim : 0.f;
                    }
        }

        __syncthreads();
        cur ^= 1;
    }

    // reduce across the 16 lanes sharing the same rows, write 2 partials
    #pragma unroll
    for (int off = 1; off < 16; off <<= 1)
        #pragma unroll
        for (int m = 0; m < 2; m++)
            #pragma unroll
            for (int i = 0; i < 4; i++) {
                pd[m][i] += __shfl_xor(pd[m][i], off);
                pp[m][i] += __shfl_xor(pp[m][i], off);
            }

    if (r16 == 0) {
        const int slot = blockIdx.x;            // 0..7
        #pragma unroll
        for (int m = 0; m < 2; m++)
            #pragma unroll
            for (int i = 0; i < 4; i++) {
                int r = rowbase + w * 32 + m * 16 + g4 * 4 + i;
                float* p = part + (size_t)r * PSTRIDE + slot;
                p[0] = pd[m][i];
                p[8] = pp[m][i];
            }
    }
}

// ---------------- Kernel C: fused rowloss + mean (single block) -------------
// 1024 threads, thread-per-row x 8 iterations. part[r][16] is one 64B line
// per row: 4x float4 loads, in-register sums, per-thread logf. Fixed-order
// accumulation + fixed-order LDS tree -> deterministic.
__global__ __launch_bounds__(1024) void tail_kernel(
    const float* __restrict__ part,
    const float* __restrict__ sq,
    const int* __restrict__ labels,
    const float* __restrict__ cnt16,
    float* __restrict__ out,
    int N) {
    __shared__ float sdata[16];
    const int tid  = threadIdx.x;
    const int lane = tid & 63;
    const int wv   = tid >> 6;

    float s = 0.f;
    for (int r = tid; r < N; r += 1024) {
        const float4 d0 = *reinterpret_cast<const float4*>(part + (size_t)r * PSTRIDE + 0);
        const float4 d1 = *reinterpret_cast<const float4*>(part + (size_t)r * PSTRIDE + 4);
        const float4 p0 = *reinterpret_cast<const float4*>(part + (size_t)r * PSTRIDE + 8);
        const float4 p1 = *reinterpret_cast<const float4*>(part + (size_t)r * PSTRIDE + 12);
        float dsum = ((d0.x + d0.y) + (d0.z + d0.w)) + ((d1.x + d1.y) + (d1.z + d1.w));
        float psum = ((p0.x + p0.y) + (p0.z + p0.w)) + ((p1.x + p1.y) + (p1.z + p1.w));

        float sqr    = sq[r];
        float possum = (psum - sqr) * M_LN2F;
        float cnt    = cnt16[labels[r]] - 1.0f;
        float dn     = dsum - __builtin_amdgcn_exp2f(sqr);  // remove diagonal
        s += -(possum - cnt * logf(dn + EPS)) / (cnt + EPS);
    }

    #pragma unroll
    for (int off = 1; off < 64; off <<= 1) s += __shfl_xor(s, off);
    if (lane == 0) sdata[wv] = s;
    __syncthreads();
    if (tid == 0) {
        float t = 0.f;
        #pragma unroll
        for (int i = 0; i < 16; i++) t += sdata[i];
        out[0] = t / (float)N;
    }
}

extern "C" void kernel_launch(void* const* d_in, const int* in_sizes, int n_in,
                              void* d_out, int out_size, void* d_ws, size_t ws_size,
                              hipStream_t stream) {
    const float* feat = (const float*)d_in[0];
    const int* labels = (const int*)d_in[1];
    const int N = in_sizes[1];

    char* ws = (char*)d_ws;
    size_t off = 0;
    ushort* fb   = (ushort*)(ws + off);  off += (size_t)N * KD * sizeof(ushort);
    float* sq    = (float*)(ws + off);   off += (size_t)N * sizeof(float);
    float* cnt16 = (float*)(ws + off);   off += (size_t)NUM_CLASSES * sizeof(float);
    float* part  = (float*)(ws + off);   off += (size_t)N * PSTRIDE * sizeof(float);

    normalize_kernel<<<(N + 3) / 4, 256, 0, stream>>>(feat, labels, fb, sq, cnt16, N);

    dim3 grid(N / (BN * NCHUNK), N / BM);             // (8, 32) = 256 blocks
    supcon_denom<<<grid, 512, 0, stream>>>(fb, labels, part, N);

    tail_kernel<<<1, 1024, 0, stream>>>(part, sq, labels, cnt16, (float*)d_out, N);
}

// Round 24
// 47.113 us; speedup vs baseline: 1.0813x; 1.0813x over previous
//
#include <hip/hip_runtime.h>
#include <hip/hip_bf16.h>

#define EPS 1e-12f
// Features stored pre-scaled by sqrt(C_EXP), C_EXP=(1/0.07)*log2(e):
// MFMA output acc = C_EXP*(f_i.f_j) is exp2-ready; possum = (pp-sq_s)*ln2.
#define SQRT_C_EXP 4.53981597f
#define M_LN2F 0.69314718056f
#define NUM_CLASSES 16

#define BM 256          // rows per denom block
#define BN 128          // cols per chunk
#define KD 128          // feature dim
#define NCHUNK 8        // col chunks per colgroup (1024 cols)
#define PSTRIDE 16      // 8 expsum + 8 possum slots per row

typedef __attribute__((ext_vector_type(4))) float f32x4;
typedef __attribute__((ext_vector_type(8))) short bf16x8;

__device__ __forceinline__ float bf2f(ushort u) {
    unsigned int x = ((unsigned int)u) << 16;
    return __uint_as_float(x);
}

// Direct global->LDS 16B/lane DMA; XOR swizzle pre-applied to the GLOBAL
// source (involution), LDS dest stays linear -> layout matches lds_frag.
__device__ __forceinline__ void gload16(const void* g, void* l) {
    __builtin_amdgcn_global_load_lds(
        (const __attribute__((address_space(1))) void*)g,
        (__attribute__((address_space(3))) void*)l, 16, 0, 0);
}

// Swizzled LDS fragment address: element (r, slot) of a [rows][128] bf16 tile,
// slot = 16B chunk within the 256B row. Swizzle: slot ^= (r&7).
__device__ __forceinline__ const bf16x8* lds_frag(const ushort* base, int r, int slot) {
    int sw = slot ^ (r & 7);
    return reinterpret_cast<const bf16x8*>(
        reinterpret_cast<const char*>(base) + r * 256 + sw * 16);
}

// ---------------- Kernel A: L2-normalize rows -> bf16 (pre-scaled) ----------
// One wave per row. Block 0 additionally computes the 16-bin label histogram
// (register counts, no atomics) -> cnt16[].
__global__ void normalize_kernel(const float* __restrict__ feat,
                                 const int* __restrict__ labels,
                                 ushort* __restrict__ fb,
                                 float* __restrict__ sq,
                                 float* __restrict__ cnt16,
                                 int N) {
    const int tid  = threadIdx.x;
    const int lane = tid & 63;
    const int w    = tid >> 6;
    int r = (blockIdx.x * blockDim.x + tid) >> 6;
    if (r < N) {
        const float2 v = *reinterpret_cast<const float2*>(feat + (size_t)r * KD + lane * 2);
        float s = v.x * v.x + v.y * v.y;
        #pragma unroll
        for (int off = 1; off < 64; off <<= 1) s += __shfl_xor(s, off);
        const float scale = SQRT_C_EXP / fmaxf(sqrtf(s), EPS);

        __hip_bfloat16 h0 = __float2bfloat16(v.x * scale);
        __hip_bfloat16 h1 = __float2bfloat16(v.y * scale);
        ushort u0 = *reinterpret_cast<ushort*>(&h0);
        ushort u1 = *reinterpret_cast<ushort*>(&h1);
        unsigned int pack = (unsigned int)u0 | ((unsigned int)u1 << 16);
        *reinterpret_cast<unsigned int*>(fb + (size_t)r * KD + lane * 2) = pack;

        float q0 = bf2f(u0), q1 = bf2f(u1);
        float q = q0 * q0 + q1 * q1;
        #pragma unroll
        for (int off = 1; off < 64; off <<= 1) q += __shfl_xor(q, off);
        if (lane == 0) sq[r] = q;                 // sq_s = C_EXP*||f||^2
    }

    if (blockIdx.x == 0) {
        int cl[NUM_CLASSES];
        #pragma unroll
        for (int c = 0; c < NUM_CLASSES; c++) cl[c] = 0;
        for (int i = tid; i < N; i += 256) {
            int lb = labels[i];
            #pragma unroll
            for (int c = 0; c < NUM_CLASSES; c++) cl[c] += (lb == c) ? 1 : 0;
        }
        #pragma unroll
        for (int c = 0; c < NUM_CLASSES; c++) {
            int v = cl[c];
            #pragma unroll
            for (int off = 1; off < 64; off <<= 1) v += __shfl_xor(v, off);
            cl[c] = v;
        }
        __shared__ int hw[4][NUM_CLASSES];
        if (lane == 0) {
            #pragma unroll
            for (int c = 0; c < NUM_CLASSES; c++) hw[w][c] = cl[c];
        }
        __syncthreads();
        if (tid < NUM_CLASSES)
            cnt16[tid] = (float)(hw[0][tid] + hw[1][tid] + hw[2][tid] + hw[3][tid]);
    }
}

// ---------------- Kernel B: fused denom+possum partials (r22 best) ----------
// 256 blocks (8 colgroups x 32 rowblocks), 512 thr = 8 waves in 8x1:
// each wave owns 32 ROWS x all 128 cols of each chunk. Live set by census:
// a[4][2]=32 + pd/pp[2][4]=16 + rlab=8 + acc[2][2]=16 + addr ~20 = ~95 regs
// -> fits the native 128 budget, A-array stays RESIDENT (no LDS remat).
__global__ __launch_bounds__(512) void supcon_denom(
    const ushort* __restrict__ fb,
    const int* __restrict__ labels,
    float* __restrict__ part,
    int N) {

    __shared__ __align__(16) ushort As[BM * KD];        // 64 KB
    __shared__ __align__(16) ushort Bs[2][BN * KD];     // 2 x 32 KB

    const int tid  = threadIdx.x;
    const int lane = tid & 63;
    const int w    = tid >> 6;        // 0..7 (32-row band)
    const int r16  = lane & 15;
    const int g4   = lane >> 4;       // 0..3

    const int rowbase = blockIdx.y * BM;
    const int col0    = blockIdx.x * (BN * NCHUNK);

    // ---- stage A tile (64KB = 8 DMA) + B chunk 0 (32KB = 4 DMA) ----
    {
        const ushort* gA = fb + (size_t)rowbase * KD;
        #pragma unroll
        for (int i = 0; i < 8; i++) {
            int d = i * 512 + tid;                  // linear 16B-chunk index
            int s = d ^ ((d >> 4) & 7);             // pre-swizzled source
            gload16(gA + (size_t)s * 8, &As[d * 8]);
        }
        const ushort* gB = fb + (size_t)col0 * KD;
        #pragma unroll
        for (int i = 0; i < 4; i++) {
            int d = i * 512 + tid;
            int s = d ^ ((d >> 4) & 7);
            gload16(gB + (size_t)s * 8, &Bs[0][d * 8]);
        }
    }

    // row labels for this lane's 8 output rows (L2-hot, overlaps DMA)
    int rlab[2][4];
    #pragma unroll
    for (int m = 0; m < 2; m++)
        #pragma unroll
        for (int i = 0; i < 4; i++)
            rlab[m][i] = labels[rowbase + w * 32 + m * 16 + g4 * 4 + i];

    __syncthreads();

    // ---- A fragments (32 rows x K=128 = 8 frags = 32 VGPR), resident ----
    bf16x8 a[4][2];                   // [ks][m], static indexing only
    #pragma unroll
    for (int ks = 0; ks < 4; ks++) {
        const int slot = ks * 4 + g4;
        #pragma unroll
        for (int m = 0; m < 2; m++)
            a[ks][m] = *lds_frag(As, w * 32 + m * 16 + r16, slot);
    }

    float pd[2][4], pp[2][4];
    #pragma unroll
    for (int m = 0; m < 2; m++)
        #pragma unroll
        for (int i = 0; i < 4; i++) { pd[m][i] = 0.f; pp[m][i] = 0.f; }

    int cur = 0;
    for (int c = 0; c < NCHUNK; c++) {
        // issue next-chunk DMA into the other buffer (drained by the barrier)
        if (c + 1 < NCHUNK) {
            const ushort* gB = fb + (size_t)(col0 + (c + 1) * BN) * KD;
            ushort* dstb = Bs[cur ^ 1];
            #pragma unroll
            for (int i = 0; i < 4; i++) {
                int d = i * 512 + tid;
                int s = d ^ ((d >> 4) & 7);
                gload16(gB + (size_t)s * 8, &dstb[d * 8]);
            }
        }

        const ushort* bbase = Bs[cur];
        const int colbase = col0 + c * BN;

        #pragma unroll 1                       // 2 cols of 16 per iteration
        for (int n2 = 0; n2 < 4; n2++) {
            int clab[2];
            #pragma unroll
            for (int j = 0; j < 2; j++)
                clab[j] = labels[colbase + (n2 * 2 + j) * 16 + r16];

            f32x4 acc[2][2];
            #pragma unroll
            for (int m = 0; m < 2; m++)
                #pragma unroll
                for (int j = 0; j < 2; j++) acc[m][j] = f32x4{0.f, 0.f, 0.f, 0.f};

            #pragma unroll
            for (int ks = 0; ks < 4; ks++) {
                const int slot = ks * 4 + g4;
                bf16x8 bv[2];
                #pragma unroll
                for (int j = 0; j < 2; j++)
                    bv[j] = *lds_frag(bbase, (n2 * 2 + j) * 16 + r16, slot);
                #pragma unroll
                for (int m = 0; m < 2; m++)
                    #pragma unroll
                    for (int j = 0; j < 2; j++)
                        acc[m][j] = __builtin_amdgcn_mfma_f32_16x16x32_bf16(a[ks][m], bv[j], acc[m][j], 0, 0, 0);
            }

            #pragma unroll
            for (int m = 0; m < 2; m++)
                #pragma unroll
                for (int j = 0; j < 2; j++)
                    #pragma unroll
                    for (int i = 0; i < 4; i++) {
                        const float sim = acc[m][j][i];
                        pd[m][i] += __builtin_amdgcn_exp2f(sim);
                        pp[m][i] += (rlab[m][i] == clab[j]) ? sim : 0.f;
                    }
        }

        __syncthreads();
        cur ^= 1;
    }

    // reduce across the 16 lanes sharing the same rows, write 2 partials
    #pragma unroll
    for (int off = 1; off < 16; off <<= 1)
        #pragma unroll
        for (int m = 0; m < 2; m++)
            #pragma unroll
            for (int i = 0; i < 4; i++) {
                pd[m][i] += __shfl_xor(pd[m][i], off);
                pp[m][i] += __shfl_xor(pp[m][i], off);
            }

    if (r16 == 0) {
        const int slot = blockIdx.x;            // 0..7
        #pragma unroll
        for (int m = 0; m < 2; m++)
            #pragma unroll
            for (int i = 0; i < 4; i++) {
                int r = rowbase + w * 32 + m * 16 + g4 * 4 + i;
                float* p = part + (size_t)r * PSTRIDE + slot;
                p[0] = pd[m][i];
                p[8] = pp[m][i];
            }
    }
}

// ---------------- Kernel C: per-row loss (one wave per row) -----------------
// part[r][16]: lanes 0-7 expsum slots, lanes 8-15 possum slots.
__global__ void rowloss_kernel(const float* __restrict__ part,
                               const float* __restrict__ sq,
                               const int* __restrict__ labels,
                               const float* __restrict__ cnt16,
                               float* __restrict__ rowloss,
                               int N) {
    int r    = (blockIdx.x * blockDim.x + threadIdx.x) >> 6;
    int lane = threadIdx.x & 63;
    if (r >= N) return;

    float v = (lane < PSTRIDE) ? part[(size_t)r * PSTRIDE + lane] : 0.f;
    #pragma unroll
    for (int off = 1; off < 8; off <<= 1) v += __shfl_xor(v, off);
    float dsum = __shfl(v, 0);
    float psum = __shfl(v, 8);

    if (lane == 0) {
        float sqr    = sq[r];
        float possum = (psum - sqr) * M_LN2F;
        float cnt    = cnt16[labels[r]] - 1.0f;
        float dn     = dsum - __builtin_amdgcn_exp2f(sqr);  // remove diagonal
        rowloss[r]   = -(possum - cnt * logf(dn + EPS)) / (cnt + EPS);
    }
}

// ---------------- Kernel D: mean (deterministic single-block reduce) --------
__global__ void reduce_kernel(const float* __restrict__ rowloss,
                              float* __restrict__ out, int N) {
    __shared__ float sdata[16];
    float s = 0.f;
    for (int r = threadIdx.x; r < N; r += blockDim.x) s += rowloss[r];
    #pragma unroll
    for (int off = 1; off < 64; off <<= 1) s += __shfl_xor(s, off);
    int wv = threadIdx.x >> 6;
    if ((threadIdx.x & 63) == 0) sdata[wv] = s;
    __syncthreads();
    if (threadIdx.x == 0) {
        float t = 0.f;
        int nw = (int)(blockDim.x >> 6);
        for (int i = 0; i < nw; i++) t += sdata[i];
        out[0] = t / (float)N;
    }
}

extern "C" void kernel_launch(void* const* d_in, const int* in_sizes, int n_in,
                              void* d_out, int out_size, void* d_ws, size_t ws_size,
                              hipStream_t stream) {
    const float* feat = (const float*)d_in[0];
    const int* labels = (const int*)d_in[1];
    const int N = in_sizes[1];

    char* ws = (char*)d_ws;
    size_t off = 0;
    ushort* fb     = (ushort*)(ws + off);  off += (size_t)N * KD * sizeof(ushort);
    float* sq      = (float*)(ws + off);   off += (size_t)N * sizeof(float);
    float* cnt16   = (float*)(ws + off);   off += (size_t)NUM_CLASSES * sizeof(float);
    float* part    = (float*)(ws + off);   off += (size_t)N * PSTRIDE * sizeof(float);
    float* rowloss = (float*)(ws + off);

    normalize_kernel<<<(N + 3) / 4, 256, 0, stream>>>(feat, labels, fb, sq, cnt16, N);

    dim3 grid(N / (BN * NCHUNK), N / BM);             // (8, 32) = 256 blocks
    supcon_denom<<<grid, 512, 0, stream>>>(fb, labels, part, N);

    rowloss_kernel<<<(N + 3) / 4, 256, 0, stream>>>(part, sq, labels, cnt16, rowloss, N);
    reduce_kernel<<<1, 1024, 0, stream>>>(rowloss, (float*)d_out, N);
}